// Round 6
// baseline (469.042 us; speedup 1.0000x reference)
//
#include <hip/hip_runtime.h>
#include <math.h>

// Problem constants (from reference)
#define HS    250      // sender hidden
#define HRr   100      // receiver hidden
#define VOC   40       // vocab, EOS = 39
#define TMAX  30       // max message length
#define NCLS  262144   // output classes
#define KS    10       // sender blocks (each owns 25 h-rows = 100 gate rows)
#define RPB   25       // h-rows per sender block
#define GRID  256      // 10 senders + 1 receiver + 245 output blocks
#define NOUT  (GRID - KS - 1)     // 245
#define CHROWS 512                // rows per output chunk (one 16-wave pass)
#define NCHUNK (NCLS / CHROWS)    // 512

typedef unsigned long long ull;

// ws layout. Packed (tag<<32 | float) regions first, 8B-aligned:
//   PK_NH : ull[2][256]  bytes [0,4096)       h exchange, dbuf by parity
//   PK_LP : ull[2][400]  bytes [4096,10496)   logit partials
//   PK_MSG: ull[30*40]   bytes [10496,20096)  message symbols (done bit in tag)
//   WS_SUMS float[64]    bytes [20096,20352)
//   PK_HR : ull[100]     bytes [20768,21568)  tagged hR words (tag==1)
//   CTRL_DONE u32        byte  21568          output-block barrier counter
// All cross-block exchange is relaxed tagged words; the ONLY fence-ish op is
// one RELEASE fetch_add per output block (round-4 lesson: acquire-per-poll
// emits L2 invalidates and melts the chip).
#define PKNH(wsp, par) ((ull*)(wsp) + (size_t)(par) * 256)
#define PKLP(wsp, par) ((ull*)(wsp) + 512 + (size_t)(par) * 400)
#define PKMSG(wsp)     ((ull*)(wsp) + 1312)
#define PKHR(wsp)      ((ull*)(wsp) + 2596)
#define WS_SUMS 5024   // float index
#define CTRL_DONE(wsp) ((unsigned*)((char*)(wsp) + 21568))
#define WS_ZERO_BYTES 21572

#define AST(p, v) __hip_atomic_store((p), (v), __ATOMIC_RELAXED, __HIP_MEMORY_SCOPE_AGENT)
#define ALD(p)    __hip_atomic_load((p), __ATOMIC_RELAXED, __HIP_MEMORY_SCOPE_AGENT)

__device__ __forceinline__ float sigf(float x) { return 1.f / (1.f + expf(-x)); }
__device__ __forceinline__ float lanebc(float v, int l) {
  return __int_as_float(__builtin_amdgcn_readlane(__float_as_int(v), l));
}
__device__ __forceinline__ ull packtv(unsigned tag, float v) {
  return ((ull)tag << 32) | (ull)__float_as_uint(v);
}
__device__ __forceinline__ float lowf(ull w) { return __uint_as_float((unsigned)w); }

#define SENDER_GATES(P, HV)                                   \
  {                                                           \
    _Pragma("unroll")                                         \
    for (int i = 0; i < 64; i += 4) {                         \
      a0 += whh[i    ] * lanebc(HV, i    );                   \
      a1 += whh[i + 1] * lanebc(HV, i + 1);                   \
      a2 += whh[i + 2] * lanebc(HV, i + 2);                   \
      a3 += whh[i + 3] * lanebc(HV, i + 3);                   \
    }                                                         \
    _Pragma("unroll")                                         \
    for (int i = 0; i < 10; i += 2) {                         \
      a0 += wih[i    ] * lanebc(sv, (P) * 10 + i    );        \
      a1 += wih[i + 1] * lanebc(sv, (P) * 10 + i + 1);        \
    }                                                         \
  }

#define RED(x) ((part[(x)] + part[100 + (x)]) + (part[200 + (x)] + part[300 + (x)]))

// ---- fused mega-kernel --------------------------------------------------
// 1024-thread blocks, single-arg __launch_bounds__(1024): the compiler MUST
// cap VGPR at 128 (16 waves x 128 = full SIMD pool), and 1 block/CU is
// architecturally guaranteed — no sender pairing (round-2/round-5 lesson),
// no 64-VGPR spill (round-3 lesson: the ",4" second arg caused it).
// blocks 0..9   : sender LSTM (round-1 structure; waves 0..7 active)
// block  10     : receiver LSTM; publishes hR as tagged words (relaxed)
// blocks 11..255: output: warm W_r HBM->LLC | poll hR | logits+exp+sums |
//                 counter barrier | inline scale (k_scale fused away).
__global__ __launch_bounds__(1024) void k_mega(
    const float* __restrict__ x,
    const float* __restrict__ W_s1,  const float* __restrict__ b_s1,
    const float* __restrict__ gum,
    const float* __restrict__ W_ih1, const float* __restrict__ W_hh1,
    const float* __restrict__ b_ih1, const float* __restrict__ b_hh1,
    const float* __restrict__ W_p,   const float* __restrict__ b_p,
    const float* __restrict__ W_ih2, const float* __restrict__ W_hh2,
    const float* __restrict__ b_ih2, const float* __restrict__ b_hh2,
    const float* __restrict__ W_r,   const float* __restrict__ b_r,
    float* __restrict__ ws,          float* __restrict__ out) {
  __shared__ float part[400];
  __shared__ float h0L[32];
  __shared__ float hx[256];     // wave-0 broadcast of exchanged h
  __shared__ float lpx[400];    // wave-0 broadcast of exchanged lp
  __shared__ float symx[VOC];   // receiver
  __shared__ int   doneL;       // receiver
  __shared__ float gL[400];     // receiver
  __shared__ float hL[HRr];     // receiver
  __shared__ float hfs[HRr];    // output: hR staging
  __shared__ float4 h4[25];     // output: hR as float4[25]
  __shared__ float  red16[16];  // output: per-wave sums

  const int b    = blockIdx.x;
  const int t0   = threadIdx.x;
  const int lane = t0 & 63;
  const int w    = t0 >> 6;     // 0..15

  if (b < KS) {
    // ================= SENDER (waves 0..7 compute; 8..15 ride barriers) ====
    const int p    = w & 3;
    const int lr   = ((w >> 2) << 6) + lane;
    const bool gact = (lr < 100) && (w < 8);
    const int gi   = lr / 25, rr = lr % 25;
    const int grow = gi * 250 + b * RPB + rr;  // global gate row

    float whh[64], wih[10], bsum = 0.f;
    if (gact) {
      #pragma unroll
      for (int i = 0; i < 64; i++) {
        int k = p * 64 + i;
        whh[i] = (k < HS) ? W_hh1[(size_t)grow * HS + k] : 0.f;
      }
      #pragma unroll
      for (int i = 0; i < 10; i++) wih[i] = W_ih1[grow * VOC + p * 10 + i];
      bsum = b_ih1[grow] + b_hh1[grow];
    }
    // wave 0: W_p slice (lane j holds W_p[j, b*25 .. +25))
    float wps[RPB];
    if (w == 0) {
      #pragma unroll
      for (int r = 0; r < RPB; r++)
        wps[r] = (lane < VOC) ? W_p[lane * HS + b * RPB + r] : 0.f;
    }
    const float bpv = (lane < VOC) ? b_p[lane] : 0.f;   // all waves (softmax)

    // ---- pre-step: h0 = relu(W_s1 @ x + b_s1), this block's 25 rows ----
    if (w < 8) {
      const int nr = (w == 7) ? 4 : 3;
      for (int j = 0; j < nr; ++j) {
        const int r = 3 * w + j;
        const float4* wr = (const float4*)(W_s1 + (size_t)(b * RPB + r) * 4096);
        const float4* xr = (const float4*)x;
        float a0 = 0.f, a1 = 0.f, a2 = 0.f, a3 = 0.f;
        #pragma unroll
        for (int q = 0; q < 16; ++q) {
          float4 w4 = wr[lane + (q << 6)], x4 = xr[lane + (q << 6)];
          a0 += w4.x * x4.x; a1 += w4.y * x4.y; a2 += w4.z * x4.z; a3 += w4.w * x4.w;
        }
        float acc = (a0 + a1) + (a2 + a3);
        #pragma unroll
        for (int o = 32; o; o >>= 1) acc += __shfl_down(acc, o);
        if (lane == 0) h0L[r] = acc + b_s1[b * RPB + r];
      }
    }
    __syncthreads();
    if (w == 0 && lane < RPB) {    // publish h(0), tag 1 (parity 1)
      float hn0 = fmaxf(h0L[lane], 0.f);
      AST(&PKNH(ws, 1)[b * RPB + lane], packtv(1u, hn0));
    }

    float c  = 0.f;   // cell state, wave0 lanes<25
    float sv = 0.f;   // current symbol, lane-distributed
    const bool h3v = (192 + lane) < HS;   // lane < 58
    const bool l6v = lane < (400 - 384);  // lane < 16

    for (int s = 0; s <= TMAX; ++s) {
      float gv = 0.f;
      if (s > 0 && lane < VOC) gv = gum[(s - 1) * VOC + lane];

      // ---- wave-0-only merged self-tag spin: h(s) + lp(s-1..), tag s+1 ----
      if (w == 0) {
        const unsigned need = (unsigned)(s + 1);
        const int par = (s + 1) & 1;
        const ull* nhp = PKNH(ws, par);
        const ull* lpp = PKLP(ws, par);
        const bool lpact = (s > 0);
        const ull dummy = (ull)need << 32;
        ull hw0, hw1, hw2, hw3;
        ull lw0 = 0, lw1 = 0, lw2 = 0, lw3 = 0, lw4 = 0, lw5 = 0, lw6 = 0;
        for (;;) {
          hw0 = ALD(&nhp[lane]);
          hw1 = ALD(&nhp[64 + lane]);
          hw2 = ALD(&nhp[128 + lane]);
          hw3 = h3v ? ALD(&nhp[192 + lane]) : dummy;
          bool ok = (unsigned)(hw0 >> 32) == need && (unsigned)(hw1 >> 32) == need &&
                    (unsigned)(hw2 >> 32) == need && (unsigned)(hw3 >> 32) == need;
          if (lpact) {
            lw0 = ALD(&lpp[lane]);        lw1 = ALD(&lpp[64 + lane]);
            lw2 = ALD(&lpp[128 + lane]);  lw3 = ALD(&lpp[192 + lane]);
            lw4 = ALD(&lpp[256 + lane]);  lw5 = ALD(&lpp[320 + lane]);
            lw6 = l6v ? ALD(&lpp[384 + lane]) : dummy;
            ok = ok && (unsigned)(lw0 >> 32) == need && (unsigned)(lw1 >> 32) == need &&
                       (unsigned)(lw2 >> 32) == need && (unsigned)(lw3 >> 32) == need &&
                       (unsigned)(lw4 >> 32) == need && (unsigned)(lw5 >> 32) == need &&
                       (unsigned)(lw6 >> 32) == need;
          }
          if (__all(ok)) break;
        }
        hx[lane] = lowf(hw0); hx[64 + lane] = lowf(hw1); hx[128 + lane] = lowf(hw2);
        if (h3v) hx[192 + lane] = lowf(hw3);
        if (lpact) {
          lpx[lane] = lowf(lw0);        lpx[64 + lane] = lowf(lw1);
          lpx[128 + lane] = lowf(lw2);  lpx[192 + lane] = lowf(lw3);
          lpx[256 + lane] = lowf(lw4);  lpx[320 + lane] = lowf(lw5);
          if (l6v) lpx[384 + lane] = lowf(lw6);
        }
      }
      __syncthreads();   // #2: broadcast hx/lpx

      float hv0 = hx[lane], hv1 = hx[64 + lane], hv2 = hx[128 + lane];
      float hv3 = h3v ? hx[192 + lane] : 0.f;

      // ---- per-wave softmax of step s-1 (redundant across waves) ----
      if (s > 0) {
        float lg = -INFINITY;
        if (lane < VOC) {
          float acc = bpv + gv;
          #pragma unroll
          for (int m = 0; m < KS; ++m) acc += lpx[m * VOC + lane];
          lg = acc;
        }
        float v = lg; int bi = lane;
        #pragma unroll
        for (int o = 32; o; o >>= 1) {      // first-max argmax (ties -> lower lane)
          float ov = __shfl_down(v, o);
          int   oi = __shfl_down(bi, o);
          if (ov > v) { v = ov; bi = oi; }
        }
        float m  = __shfl(v, 0);
        int  idx = __shfl(bi, 0);
        float e = (lane < VOC) ? expf(lg - m) : 0.f;
        float ssum = e;
        #pragma unroll
        for (int o = 32; o; o >>= 1) ssum += __shfl_down(ssum, o);
        ssum = __shfl(ssum, 0);
        float soft = e / ssum;
        float hard = (lane == idx) ? 1.f : 0.f;
        float st   = (hard + soft) - soft;           // exact ST forward ordering
        const bool last = (s - 1 == TMAX - 1);
        float emit = last ? ((lane == VOC - 1) ? 1.f : 0.f) : st;
        const bool done = (idx == VOC - 1) || last;
        if (b == 0 && w == 0 && lane < VOC)
          AST(&PKMSG(ws)[(s - 1) * VOC + lane],
              packtv((unsigned)s | (done ? 0x10000u : 0u), emit));
        sv = (lane < VOC) ? emit : 0.f;
        if (done) break;                             // uniform across waves/blocks
      }

      // ---- gate partials: 100 rows x k-slice, waves 0..7 ----
      if (gact) {
        float a0 = bsum, a1 = 0.f, a2 = 0.f, a3 = 0.f;
        if      (p == 0) SENDER_GATES(0, hv0)
        else if (p == 1) SENDER_GATES(1, hv1)
        else if (p == 2) SENDER_GATES(2, hv2)
        else             SENDER_GATES(3, hv3)
        part[p * 100 + lr] = (a0 + a1) + (a2 + a3);
      }
      __syncthreads();   // #1

      // ---- wave-0: reduce, h/c update, logit partial, publish tag s+2 ----
      if (w == 0) {
        float gi_ = RED(lane < RPB ? lane : 0);
        float gf_ = RED(25 + (lane < RPB ? lane : 0));
        float gg_ = RED(50 + (lane < RPB ? lane : 0));
        float go_ = RED(75 + (lane < RPB ? lane : 0));
        float ig = sigf(gi_), fg = sigf(gf_), gg = tanhf(gg_), og = sigf(go_);
        float cn = fg * c + ig * gg; c = cn;
        float hn = og * tanhf(cn);
        float lpsum = 0.f;
        #pragma unroll
        for (int r = 0; r < RPB; ++r) lpsum += wps[r] * lanebc(hn, r);
        const unsigned nt = (unsigned)(s + 2);
        const int np = (s + 2) & 1;
        if (lane < RPB) AST(&PKNH(ws, np)[b * RPB + lane], packtv(nt, hn));
        if (lane < VOC) AST(&PKLP(ws, np)[b * VOC + lane], packtv(nt, lpsum));
      }
    }
  } else if (b == KS) {
    // ================= RECEIVER (concurrent consumer) =================
    const bool act = (t0 < 400);
    float wih2[VOC], whh2[HRr], bsum2 = 0.f;
    if (act) {
      #pragma unroll
      for (int i = 0; i < VOC; i++) wih2[i] = W_ih2[t0 * VOC + i];
      #pragma unroll
      for (int i = 0; i < HRr; i++) whh2[i] = W_hh2[t0 * HRr + i];
      bsum2 = b_ih2[t0] + b_hh2[t0];
    }
    float c2 = 0.f, rv0 = 0.f, rv1 = 0.f;

    for (int t = 0; t < TMAX; ++t) {
      // ---- wave-0-only spin on tagged message words ----
      if (w == 0) {
        const bool mv = (lane < VOC);
        ull mw = 0;
        for (;;) {
          if (mv) mw = ALD(&PKMSG(ws)[t * VOC + lane]);
          bool ok = !mv || ((unsigned)(mw >> 32) & 0xFFFFu) == (unsigned)(t + 1);
          if (__all(ok)) break;
        }
        if (mv) symx[lane] = lowf(mw);
        if (lane == 0) doneL = (int)(((unsigned)(mw >> 32)) >> 16);
      }
      __syncthreads();
      const bool done = (doneL != 0);
      float sv2 = (lane < VOC) ? symx[lane] : 0.f;
      if (act) {
        float a0 = bsum2, a1 = 0.f, a2 = 0.f, a3 = 0.f;
        #pragma unroll
        for (int i = 0; i < VOC; i += 4) {
          a0 += wih2[i    ] * lanebc(sv2, i    );
          a1 += wih2[i + 1] * lanebc(sv2, i + 1);
          a2 += wih2[i + 2] * lanebc(sv2, i + 2);
          a3 += wih2[i + 3] * lanebc(sv2, i + 3);
        }
        #pragma unroll
        for (int i = 0; i < 64; i += 4) {
          a0 += whh2[i    ] * lanebc(rv0, i    );
          a1 += whh2[i + 1] * lanebc(rv0, i + 1);
          a2 += whh2[i + 2] * lanebc(rv0, i + 2);
          a3 += whh2[i + 3] * lanebc(rv0, i + 3);
        }
        #pragma unroll
        for (int i = 0; i < 36; i += 4) {
          a0 += whh2[64 + i    ] * lanebc(rv1, i    );
          a1 += whh2[64 + i + 1] * lanebc(rv1, i + 1);
          a2 += whh2[64 + i + 2] * lanebc(rv1, i + 2);
          a3 += whh2[64 + i + 3] * lanebc(rv1, i + 3);
        }
        gL[t0] = (a0 + a1) + (a2 + a3);
      }
      __syncthreads();
      if (t0 < HRr) {
        float ig = sigf(gL[t0]);
        float fg = sigf(gL[100 + t0]);
        float gg = tanhf(gL[200 + t0]);
        float og = sigf(gL[300 + t0]);
        float cn = fg * c2 + ig * gg; c2 = cn;
        hL[t0] = og * tanhf(cn);
      }
      __syncthreads();
      rv0 = hL[lane];
      rv1 = (lane < 36) ? hL[64 + lane] : 0.f;
      if (done) break;
    }
    // publish hR as tagged words — same relaxed protocol as PKNH/PKMSG
    if (t0 < HRr) AST(&PKHR(ws)[t0], packtv(1u, hL[t0]));
  } else {
    // ================= OUTPUT (overlapped with sender) =================
    const int o = b - KS - 1;             // 0..244
    // phase 1: warm this block's W_r chunks into LLC/L2 (keep-alive sink)
    float dummy = 0.f;
    const float4* wr4 = (const float4*)W_r;
    for (int c = o; c < NCHUNK; c += NOUT) {
      const int f0 = c * (CHROWS * 25);   // 512 rows * 25 float4
      for (int i = f0 + t0; i < f0 + CHROWS * 25; i += 1024) {
        float4 w4 = wr4[i];
        dummy += (w4.x + w4.y) + (w4.z + w4.w);
      }
    }
    asm volatile("" :: "v"(dummy));       // keep warm loads alive

    // phase 2: relaxed per-thread poll of tagged hR words (NO acquire),
    // coarse s_sleep to keep poll traffic off the LLC while sender runs.
    if (t0 < HRr) {
      ull hw;
      for (;;) {
        hw = ALD(&PKHR(ws)[t0]);
        if ((unsigned)(hw >> 32) == 1u) break;
        __builtin_amdgcn_s_sleep(128);
      }
      hfs[t0] = lowf(hw);
    }
    __syncthreads();
    if (t0 < 25)
      h4[t0] = make_float4(hfs[4*t0], hfs[4*t0+1], hfs[4*t0+2], hfs[4*t0+3]);
    __syncthreads();

    // phase 3: logits + exp + partial sums from cache-resident W_r.
    // 1024 threads = four 256-thread sub-units, each = one k_out body.
    const int sub = t0 >> 8;              // 0..3
    const int tl  = t0 & 255;
    const int wv  = tl >> 6;              // 0..3 within sub
    const int sl  = lane & 31;
    const int hf  = lane >> 5;
    float accs = 0.f;
    for (int c = o; c < NCHUNK; c += NOUT) {
      const int base = c * CHROWS + sub * 128 + wv * 32;
      #pragma unroll 4
      for (int i = 0; i < 16; ++i) {
        const int row = base + 2 * i + hf;
        float v = 0.f;
        if (sl < 25) {
          float4 w4 = wr4[(size_t)row * 25 + sl];
          float4 hq = h4[sl];
          v = w4.x * hq.x + w4.y * hq.y + w4.z * hq.z + w4.w * hq.w;
        }
        #pragma unroll
        for (int off = 16; off; off >>= 1) v += __shfl_down(v, off, 32);
        float e = 0.f;
        if (sl == 0) { e = expf(v + b_r[row]); accs += e; }
        float eB = __shfl(e, 32);
        if (lane == 0) ((float2*)out)[(base + 2 * i) >> 1] = make_float2(e, eB);
      }
    }
    accs += __shfl_down(accs, 32);        // lane0 += lane32
    if (lane == 0) red16[w] = accs;
    __syncthreads();
    if (t0 == 0) {
      float tot = (((red16[0] + red16[1]) + (red16[2] + red16[3])) +
                   ((red16[4] + red16[5]) + (red16[6] + red16[7]))) +
                  (((red16[8] + red16[9]) + (red16[10] + red16[11])) +
                   ((red16[12] + red16[13]) + (red16[14] + red16[15])));
      atomicAdd(&ws[WS_SUMS + (b & 63)], tot);
      // one-time RELEASE add: orders the partial-sum add before the count
      __hip_atomic_fetch_add(CTRL_DONE(ws), 1u, __ATOMIC_RELEASE,
                             __HIP_MEMORY_SCOPE_AGENT);
      while (__hip_atomic_load(CTRL_DONE(ws), __ATOMIC_RELAXED,
                               __HIP_MEMORY_SCOPE_AGENT) < (unsigned)NOUT)
        __builtin_amdgcn_s_sleep(8);
    }
    __syncthreads();

    // fused k_scale: sums via LLC-direct relaxed loads (no cache concerns),
    // bit-identical shfl_xor tree to the old k_scale kernel.
    if (t0 < 128) {
      float s = __uint_as_float(ALD((const unsigned*)(ws + WS_SUMS) + (lane & 63)));
      #pragma unroll
      for (int off = 1; off < 64; off <<= 1) s += __shfl_xor(s, off);
      const float rinv = 1.f / s;
      float4* po = (float4*)out;
      for (int c = o; c < NCHUNK; c += NOUT) {
        float4 e = po[c * 128 + t0];      // own writes, L1/L2-hot
        e.x *= rinv; e.y *= rinv; e.z *= rinv; e.w *= rinv;
        po[c * 128 + t0] = e;
      }
    }
  }
}

extern "C" void kernel_launch(void* const* d_in, const int* in_sizes, int n_in,
                              void* d_out, int out_size, void* d_ws, size_t ws_size,
                              hipStream_t stream) {
  const float* x     = (const float*)d_in[0];
  const float* gum   = (const float*)d_in[1];
  const float* W_s1  = (const float*)d_in[2];
  const float* b_s1  = (const float*)d_in[3];
  const float* W_ih1 = (const float*)d_in[4];
  const float* W_hh1 = (const float*)d_in[5];
  const float* b_ih1 = (const float*)d_in[6];
  const float* b_hh1 = (const float*)d_in[7];
  const float* W_p   = (const float*)d_in[8];
  const float* b_p   = (const float*)d_in[9];
  const float* W_ih2 = (const float*)d_in[10];
  const float* W_hh2 = (const float*)d_in[11];
  const float* b_ih2 = (const float*)d_in[12];
  const float* b_hh2 = (const float*)d_in[13];
  const float* W_r   = (const float*)d_in[14];
  const float* b_r   = (const float*)d_in[15];
  float* ws  = (float*)d_ws;
  float* out = (float*)d_out;

  // zero packed tag regions + sum slots + hR tags + done counter
  (void)hipMemsetAsync(d_ws, 0, WS_ZERO_BYTES, stream);
  k_mega <<<GRID, 1024, 0, stream>>>(x, W_s1, b_s1, gum, W_ih1, W_hh1,
                                     b_ih1, b_hh1, W_p, b_p,
                                     W_ih2, W_hh2, b_ih2, b_hh2,
                                     W_r, b_r, ws, out);
}

// Round 7
// 346.737 us; speedup vs baseline: 1.3527x; 1.3527x over previous
//
#include <hip/hip_runtime.h>
#include <math.h>

// Problem constants (from reference)
#define HS    250      // sender hidden
#define HRr   100      // receiver hidden
#define VOC   40       // vocab, EOS = 39
#define TMAX  30       // max message length
#define NCLS  262144   // output classes
#define KS    10       // sender blocks (each owns 25 h-rows = 100 gate rows)
#define RPB   25       // h-rows per sender block

// k_out2 geometry
#define OB    512               // output blocks
#define ORPB  (NCLS / OB)       // 512 rows per block
#define OTIL  128               // rows per LDS tile
#define NTIL  (ORPB / OTIL)     // 4 tiles
#define LDST  129               // padded LDS stride (floats): 129%32==1 -> 2-way (free)

typedef unsigned long long ull;

// ws layout. Packed (tag<<32 | float) regions first, 8B-aligned:
//   PK_NH : ull[2][256]  h exchange, double-buffered by tag parity
//   PK_LP : ull[2][400]  logit partials, double-buffered
//   PK_MSG: ull[30*40]   message symbols (tag carries done bit)
// Floats after: WS_SUMS float[64] @byte 20096; WS_HR float[100] @byte 20352.
// CTRL_DONE u32 @byte 20752 (output-block barrier counter).
#define PKNH(wsp, par) ((ull*)(wsp) + (size_t)(par) * 256)
#define PKLP(wsp, par) ((ull*)(wsp) + 512 + (size_t)(par) * 400)
#define PKMSG(wsp)     ((ull*)(wsp) + 1312)
#define WS_SUMS 5024   // float index
#define WS_HR   5088   // float index (byte 20352, 16B aligned)
#define CTRL_DONE(wsp) ((unsigned*)((char*)(wsp) + 20752))
#define WS_ZERO_BYTES 20756

#define AST(p, v) __hip_atomic_store((p), (v), __ATOMIC_RELAXED, __HIP_MEMORY_SCOPE_AGENT)
#define ALD(p)    __hip_atomic_load((p), __ATOMIC_RELAXED, __HIP_MEMORY_SCOPE_AGENT)

__device__ __forceinline__ float sigf(float x) { return 1.f / (1.f + expf(-x)); }
__device__ __forceinline__ float lanebc(float v, int l) {
  return __int_as_float(__builtin_amdgcn_readlane(__float_as_int(v), l));
}
__device__ __forceinline__ ull packtv(unsigned tag, float v) {
  return ((ull)tag << 32) | (ull)__float_as_uint(v);
}
__device__ __forceinline__ float lowf(ull w) { return __uint_as_float((unsigned)w); }

#define SENDER_GATES(P, HV)                                   \
  {                                                           \
    _Pragma("unroll")                                         \
    for (int i = 0; i < 64; i += 4) {                         \
      a0 += whh[i    ] * lanebc(HV, i    );                   \
      a1 += whh[i + 1] * lanebc(HV, i + 1);                   \
      a2 += whh[i + 2] * lanebc(HV, i + 2);                   \
      a3 += whh[i + 3] * lanebc(HV, i + 3);                   \
    }                                                         \
    _Pragma("unroll")                                         \
    for (int i = 0; i < 10; i += 2) {                         \
      a0 += wih[i    ] * lanebc(sv, (P) * 10 + i    );        \
      a1 += wih[i + 1] * lanebc(sv, (P) * 10 + i + 1);        \
    }                                                         \
  }

#define RED(x) ((part[(x)] + part[100 + (x)]) + (part[200 + (x)] + part[300 + (x)]))

// ---------------- kernel 1: h0 + sender (blocks 0..9) + receiver (10) ------
// EXACT round-1 structure (proven 121 us, VGPR=128, no spill).
__global__ __launch_bounds__(512, 2) void k_sender(
    const float* __restrict__ x,
    const float* __restrict__ W_s1,  const float* __restrict__ b_s1,
    const float* __restrict__ gum,
    const float* __restrict__ W_ih1, const float* __restrict__ W_hh1,
    const float* __restrict__ b_ih1, const float* __restrict__ b_hh1,
    const float* __restrict__ W_p,   const float* __restrict__ b_p,
    const float* __restrict__ W_ih2, const float* __restrict__ W_hh2,
    const float* __restrict__ b_ih2, const float* __restrict__ b_hh2,
    float* __restrict__ ws) {
  __shared__ float part[400];
  __shared__ float h0L[32];
  __shared__ float hx[256];     // wave-0 broadcast of exchanged h
  __shared__ float lpx[400];    // wave-0 broadcast of exchanged lp
  __shared__ float symx[VOC];   // receiver
  __shared__ int   doneL;       // receiver
  __shared__ float gL[400];     // receiver
  __shared__ float hL[HRr];     // receiver

  const int b    = blockIdx.x;
  const int t0   = threadIdx.x;
  const int lane = t0 & 63;
  const int w    = t0 >> 6;

  if (b < KS) {
    // ================= SENDER =================
    const int p    = w & 3;
    const int lr   = ((w >> 2) << 6) + lane;   // 0..127
    const bool gact = (lr < 100);
    const int gi   = lr / 25, rr = lr % 25;
    const int grow = gi * 250 + b * RPB + rr;  // global gate row

    float whh[64], wih[10], bsum = 0.f;
    if (gact) {
      #pragma unroll
      for (int i = 0; i < 64; i++) {
        int k = p * 64 + i;
        whh[i] = (k < HS) ? W_hh1[(size_t)grow * HS + k] : 0.f;
      }
      #pragma unroll
      for (int i = 0; i < 10; i++) wih[i] = W_ih1[grow * VOC + p * 10 + i];
      bsum = b_ih1[grow] + b_hh1[grow];
    }
    // wave 0: W_p slice (lane j holds W_p[j, b*25 .. +25))
    float wps[RPB];
    if (w == 0) {
      #pragma unroll
      for (int r = 0; r < RPB; r++)
        wps[r] = (lane < VOC) ? W_p[lane * HS + b * RPB + r] : 0.f;
    }
    const float bpv = (lane < VOC) ? b_p[lane] : 0.f;   // all waves (softmax)

    // ---- pre-step: h0 = relu(W_s1 @ x + b_s1), this block's 25 rows ----
    {
      const int nr = (w == 7) ? 4 : 3;
      for (int j = 0; j < nr; ++j) {
        const int r = 3 * w + j;
        const float4* wr = (const float4*)(W_s1 + (size_t)(b * RPB + r) * 4096);
        const float4* xr = (const float4*)x;
        float a0 = 0.f, a1 = 0.f, a2 = 0.f, a3 = 0.f;
        #pragma unroll
        for (int q = 0; q < 16; ++q) {
          float4 w4 = wr[lane + (q << 6)], x4 = xr[lane + (q << 6)];
          a0 += w4.x * x4.x; a1 += w4.y * x4.y; a2 += w4.z * x4.z; a3 += w4.w * x4.w;
        }
        float acc = (a0 + a1) + (a2 + a3);
        #pragma unroll
        for (int o = 32; o; o >>= 1) acc += __shfl_down(acc, o);
        if (lane == 0) h0L[r] = acc + b_s1[b * RPB + r];
      }
    }
    __syncthreads();
    if (w == 0 && lane < RPB) {    // publish h(0), tag 1 (parity 1)
      float hn0 = fmaxf(h0L[lane], 0.f);
      AST(&PKNH(ws, 1)[b * RPB + lane], packtv(1u, hn0));
    }

    float c  = 0.f;   // cell state, wave0 lanes<25
    float sv = 0.f;   // current symbol, lane-distributed
    const bool h3v = (192 + lane) < HS;   // lane < 58
    const bool l6v = lane < (400 - 384);  // lane < 16

    for (int s = 0; s <= TMAX; ++s) {
      float gv = 0.f;
      if (s > 0 && lane < VOC) gv = gum[(s - 1) * VOC + lane];

      // ---- wave-0-only merged self-tag spin: h(s) + lp(s-1..), tag s+1 ----
      if (w == 0) {
        const unsigned need = (unsigned)(s + 1);
        const int par = (s + 1) & 1;
        const ull* nhp = PKNH(ws, par);
        const ull* lpp = PKLP(ws, par);
        const bool lpact = (s > 0);
        const ull dummy = (ull)need << 32;
        ull hw0, hw1, hw2, hw3;
        ull lw0 = 0, lw1 = 0, lw2 = 0, lw3 = 0, lw4 = 0, lw5 = 0, lw6 = 0;
        for (;;) {
          hw0 = ALD(&nhp[lane]);
          hw1 = ALD(&nhp[64 + lane]);
          hw2 = ALD(&nhp[128 + lane]);
          hw3 = h3v ? ALD(&nhp[192 + lane]) : dummy;
          bool ok = (unsigned)(hw0 >> 32) == need && (unsigned)(hw1 >> 32) == need &&
                    (unsigned)(hw2 >> 32) == need && (unsigned)(hw3 >> 32) == need;
          if (lpact) {
            lw0 = ALD(&lpp[lane]);        lw1 = ALD(&lpp[64 + lane]);
            lw2 = ALD(&lpp[128 + lane]);  lw3 = ALD(&lpp[192 + lane]);
            lw4 = ALD(&lpp[256 + lane]);  lw5 = ALD(&lpp[320 + lane]);
            lw6 = l6v ? ALD(&lpp[384 + lane]) : dummy;
            ok = ok && (unsigned)(lw0 >> 32) == need && (unsigned)(lw1 >> 32) == need &&
                       (unsigned)(lw2 >> 32) == need && (unsigned)(lw3 >> 32) == need &&
                       (unsigned)(lw4 >> 32) == need && (unsigned)(lw5 >> 32) == need &&
                       (unsigned)(lw6 >> 32) == need;
          }
          if (__all(ok)) break;
        }
        hx[lane] = lowf(hw0); hx[64 + lane] = lowf(hw1); hx[128 + lane] = lowf(hw2);
        if (h3v) hx[192 + lane] = lowf(hw3);
        if (lpact) {
          lpx[lane] = lowf(lw0);        lpx[64 + lane] = lowf(lw1);
          lpx[128 + lane] = lowf(lw2);  lpx[192 + lane] = lowf(lw3);
          lpx[256 + lane] = lowf(lw4);  lpx[320 + lane] = lowf(lw5);
          if (l6v) lpx[384 + lane] = lowf(lw6);
        }
      }
      __syncthreads();   // #2: broadcast hx/lpx

      float hv0 = hx[lane], hv1 = hx[64 + lane], hv2 = hx[128 + lane];
      float hv3 = h3v ? hx[192 + lane] : 0.f;

      // ---- per-wave softmax of step s-1 (redundant across waves) ----
      if (s > 0) {
        float lg = -INFINITY;
        if (lane < VOC) {
          float acc = bpv + gv;
          #pragma unroll
          for (int m = 0; m < KS; ++m) acc += lpx[m * VOC + lane];
          lg = acc;
        }
        float v = lg; int bi = lane;
        #pragma unroll
        for (int o = 32; o; o >>= 1) {      // first-max argmax (ties -> lower lane)
          float ov = __shfl_down(v, o);
          int   oi = __shfl_down(bi, o);
          if (ov > v) { v = ov; bi = oi; }
        }
        float m  = __shfl(v, 0);
        int  idx = __shfl(bi, 0);
        float e = (lane < VOC) ? expf(lg - m) : 0.f;
        float ssum = e;
        #pragma unroll
        for (int o = 32; o; o >>= 1) ssum += __shfl_down(ssum, o);
        ssum = __shfl(ssum, 0);
        float soft = e / ssum;
        float hard = (lane == idx) ? 1.f : 0.f;
        float st   = (hard + soft) - soft;           // exact ST forward ordering
        const bool last = (s - 1 == TMAX - 1);
        float emit = last ? ((lane == VOC - 1) ? 1.f : 0.f) : st;
        const bool done = (idx == VOC - 1) || last;
        if (b == 0 && w == 0 && lane < VOC)
          AST(&PKMSG(ws)[(s - 1) * VOC + lane],
              packtv((unsigned)s | (done ? 0x10000u : 0u), emit));
        sv = (lane < VOC) ? emit : 0.f;
        if (done) break;                             // uniform across waves/blocks
      }

      // ---- gate partials: 100 rows x k-slice, all 8 waves ----
      if (gact) {
        float a0 = bsum, a1 = 0.f, a2 = 0.f, a3 = 0.f;
        if      (p == 0) SENDER_GATES(0, hv0)
        else if (p == 1) SENDER_GATES(1, hv1)
        else if (p == 2) SENDER_GATES(2, hv2)
        else             SENDER_GATES(3, hv3)
        part[p * 100 + lr] = (a0 + a1) + (a2 + a3);
      }
      __syncthreads();   // #1

      // ---- wave-0: reduce, h/c update, logit partial, publish tag s+2 ----
      if (w == 0) {
        float gi_ = RED(lane < RPB ? lane : 0);
        float gf_ = RED(25 + (lane < RPB ? lane : 0));
        float gg_ = RED(50 + (lane < RPB ? lane : 0));
        float go_ = RED(75 + (lane < RPB ? lane : 0));
        float ig = sigf(gi_), fg = sigf(gf_), gg = tanhf(gg_), og = sigf(go_);
        float cn = fg * c + ig * gg; c = cn;
        float hn = og * tanhf(cn);
        float lpsum = 0.f;
        #pragma unroll
        for (int r = 0; r < RPB; ++r) lpsum += wps[r] * lanebc(hn, r);
        const unsigned nt = (unsigned)(s + 2);
        const int np = (s + 2) & 1;
        if (lane < RPB) AST(&PKNH(ws, np)[b * RPB + lane], packtv(nt, hn));
        if (lane < VOC) AST(&PKLP(ws, np)[b * VOC + lane], packtv(nt, lpsum));
      }
    }
  } else {
    // ================= RECEIVER (concurrent consumer) =================
    const bool act = (t0 < 400);
    float wih2[VOC], whh2[HRr], bsum2 = 0.f;
    if (act) {
      #pragma unroll
      for (int i = 0; i < VOC; i++) wih2[i] = W_ih2[t0 * VOC + i];
      #pragma unroll
      for (int i = 0; i < HRr; i++) whh2[i] = W_hh2[t0 * HRr + i];
      bsum2 = b_ih2[t0] + b_hh2[t0];
    }
    float c2 = 0.f, rv0 = 0.f, rv1 = 0.f;

    for (int t = 0; t < TMAX; ++t) {
      // ---- wave-0-only spin on tagged message words ----
      if (w == 0) {
        const bool mv = (lane < VOC);
        ull mw = 0;
        for (;;) {
          if (mv) mw = ALD(&PKMSG(ws)[t * VOC + lane]);
          bool ok = !mv || ((unsigned)(mw >> 32) & 0xFFFFu) == (unsigned)(t + 1);
          if (__all(ok)) break;
        }
        if (mv) symx[lane] = lowf(mw);
        if (lane == 0) doneL = (int)(((unsigned)(mw >> 32)) >> 16);
      }
      __syncthreads();
      const bool done = (doneL != 0);
      float sv2 = (lane < VOC) ? symx[lane] : 0.f;
      if (act) {
        float a0 = bsum2, a1 = 0.f, a2 = 0.f, a3 = 0.f;
        #pragma unroll
        for (int i = 0; i < VOC; i += 4) {
          a0 += wih2[i    ] * lanebc(sv2, i    );
          a1 += wih2[i + 1] * lanebc(sv2, i + 1);
          a2 += wih2[i + 2] * lanebc(sv2, i + 2);
          a3 += wih2[i + 3] * lanebc(sv2, i + 3);
        }
        #pragma unroll
        for (int i = 0; i < 64; i += 4) {
          a0 += whh2[i    ] * lanebc(rv0, i    );
          a1 += whh2[i + 1] * lanebc(rv0, i + 1);
          a2 += whh2[i + 2] * lanebc(rv0, i + 2);
          a3 += whh2[i + 3] * lanebc(rv0, i + 3);
        }
        #pragma unroll
        for (int i = 0; i < 36; i += 4) {
          a0 += whh2[64 + i    ] * lanebc(rv1, i    );
          a1 += whh2[64 + i + 1] * lanebc(rv1, i + 1);
          a2 += whh2[64 + i + 2] * lanebc(rv1, i + 2);
          a3 += whh2[64 + i + 3] * lanebc(rv1, i + 3);
        }
        gL[t0] = (a0 + a1) + (a2 + a3);
      }
      __syncthreads();
      if (t0 < HRr) {
        float ig = sigf(gL[t0]);
        float fg = sigf(gL[100 + t0]);
        float gg = tanhf(gL[200 + t0]);
        float og = sigf(gL[300 + t0]);
        float cn = fg * c2 + ig * gg; c2 = cn;
        hL[t0] = og * tanhf(cn);
      }
      __syncthreads();
      rv0 = hL[lane];
      rv1 = (lane < 36) ? hL[64 + lane] : 0.f;
      if (done) break;
    }
    if (t0 < HRr) ws[WS_HR + t0] = hL[t0];
  }
}

// ---------------- kernel 2: logits + exp + softmax-scale (fused) -----------
// LDS-tiled: coalesced 64-lane float4 loads of W_r into a TRANSPOSED padded
// tile (stride 129 -> 2-way bank access = free), conflict-free compute reads.
// Fused normalization via relaxed done-counter barrier (proven in round 6).
__global__ __launch_bounds__(256) void k_out2(
    const float* __restrict__ W_r, const float* __restrict__ b_r,
    float* __restrict__ ws, float* __restrict__ out) {
  __shared__ float ldsT[100 * LDST];   // 51.6 KB transposed tile [k][r]
  __shared__ float hsh[HRr];
  __shared__ float part2[OTIL];
  __shared__ float redw[2];

  const int t0   = threadIdx.x;
  const int lane = t0 & 63;
  const int w    = t0 >> 6;
  const int b    = blockIdx.x;

  if (t0 < HRr) hsh[t0] = ws[WS_HR + t0];   // kernel boundary = synced
  __syncthreads();

  const float4* wr4 = (const float4*)W_r;
  const int rloc  = t0 & (OTIL - 1);        // row within tile (compute)
  const int khalf = (t0 >> 7) * 50;         // 0 (threads<128) or 50
  float accs = 0.f;                         // per-thread exp partial sum

  for (int tile = 0; tile < NTIL; ++tile) {
    const int row0 = b * ORPB + tile * OTIL;
    // ---- load + transpose: 3200 float4 (= 128 rows x 25), coalesced ----
    #pragma unroll
    for (int it = 0; it < 13; ++it) {
      const int j = t0 + it * 256;
      if (j < OTIL * 25) {
        float4 v = wr4[(size_t)row0 * 25 + j];
        const int r = j / 25, c = j % 25;
        float* p = &ldsT[(4 * c) * LDST + r];
        p[0]        = v.x;
        p[LDST]     = v.y;
        p[2 * LDST] = v.z;
        p[3 * LDST] = v.w;
      }
    }
    __syncthreads();
    // ---- compute: each (row, k-half) pair; conflict-free LDS reads ----
    float a0 = 0.f, a1 = 0.f;
    #pragma unroll
    for (int k = 0; k < 50; k += 2) {
      a0 += ldsT[(khalf + k    ) * LDST + rloc] * hsh[khalf + k    ];
      a1 += ldsT[(khalf + k + 1) * LDST + rloc] * hsh[khalf + k + 1];
    }
    const float acc = a0 + a1;
    if (t0 >= OTIL) part2[rloc] = acc;
    __syncthreads();
    if (t0 < OTIL) {
      const int row = row0 + t0;
      float e = expf(acc + part2[t0] + b_r[row]);
      out[row] = e;
      accs += e;
    }
    __syncthreads();   // protect ldsT/part2 before next tile
  }

  // ---- block partial sum (threads 0..127 hold accs) -> one atomic ----
  float s = accs;
  #pragma unroll
  for (int o = 32; o; o >>= 1) s += __shfl_down(s, o);
  if (lane == 0 && w < 2) redw[w] = s;
  __syncthreads();
  if (t0 == 0) {
    atomicAdd(&ws[WS_SUMS + (b & 63)], redw[0] + redw[1]);
    // RELEASE add orders the partial-sum atomic before the counter bump;
    // poll side stays RELAXED (round-4 lesson: acquire-per-poll = L2 melt).
    __hip_atomic_fetch_add(CTRL_DONE(ws), 1u, __ATOMIC_RELEASE,
                           __HIP_MEMORY_SCOPE_AGENT);
    while (__hip_atomic_load(CTRL_DONE(ws), __ATOMIC_RELAXED,
                             __HIP_MEMORY_SCOPE_AGENT) < (unsigned)OB)
      __builtin_amdgcn_s_sleep(4);
  }
  __syncthreads();

  // ---- fused scale: global sum via LLC-direct relaxed loads ----
  float ssum = __uint_as_float(ALD((const unsigned*)(ws + WS_SUMS) + (lane & 63)));
  #pragma unroll
  for (int off = 1; off < 64; off <<= 1) ssum += __shfl_xor(ssum, off);
  const float rinv = 1.f / ssum;
  // rescale own 512 rows (128 float4, written by this block -> L1/L2-hot)
  if (t0 < 128) {
    float4* po = (float4*)out;
    float4 e = po[b * 128 + t0];
    e.x *= rinv; e.y *= rinv; e.z *= rinv; e.w *= rinv;
    po[b * 128 + t0] = e;
  }
}

extern "C" void kernel_launch(void* const* d_in, const int* in_sizes, int n_in,
                              void* d_out, int out_size, void* d_ws, size_t ws_size,
                              hipStream_t stream) {
  const float* x     = (const float*)d_in[0];
  const float* gum   = (const float*)d_in[1];
  const float* W_s1  = (const float*)d_in[2];
  const float* b_s1  = (const float*)d_in[3];
  const float* W_ih1 = (const float*)d_in[4];
  const float* W_hh1 = (const float*)d_in[5];
  const float* b_ih1 = (const float*)d_in[6];
  const float* b_hh1 = (const float*)d_in[7];
  const float* W_p   = (const float*)d_in[8];
  const float* b_p   = (const float*)d_in[9];
  const float* W_ih2 = (const float*)d_in[10];
  const float* W_hh2 = (const float*)d_in[11];
  const float* b_ih2 = (const float*)d_in[12];
  const float* b_hh2 = (const float*)d_in[13];
  const float* W_r   = (const float*)d_in[14];
  const float* b_r   = (const float*)d_in[15];
  float* ws  = (float*)d_ws;
  float* out = (float*)d_out;

  // zero packed tag regions + sum slots + done counter (ws re-poisoned 0xAA)
  (void)hipMemsetAsync(d_ws, 0, WS_ZERO_BYTES, stream);
  k_sender<<<KS + 1, 512, 0, stream>>>(x, W_s1, b_s1, gum, W_ih1, W_hh1,
                                       b_ih1, b_hh1, W_p, b_p,
                                       W_ih2, W_hh2, b_ih2, b_hh2, ws);
  k_out2  <<<OB,     256, 0, stream>>>(W_r, b_r, ws, out);
}

// Round 8
// 320.497 us; speedup vs baseline: 1.4635x; 1.0819x over previous
//
#include <hip/hip_runtime.h>
#include <math.h>

// Problem constants (from reference)
#define HS    250      // sender hidden
#define HRr   100      // receiver hidden
#define VOC   40       // vocab, EOS = 39
#define TMAX  30       // max message length
#define NCLS  262144   // output classes
#define KS    10       // sender blocks (each owns 25 h-rows = 100 gate rows)
#define RPB   25       // h-rows per sender block

typedef unsigned long long ull;

// ws layout. Packed (tag<<32 | float) regions first, 8B-aligned:
//   PK_NH : ull[2][256]  h exchange, double-buffered by tag parity
//   PK_LP : ull[2][400]  logit partials, double-buffered
//   PK_MSG: ull[30*40]   message symbols (tag carries done bit)
// Floats after: WS_SUMS float[64] @byte 20096; WS_HR float[100] @byte 20352.
#define PKNH(wsp, par) ((ull*)(wsp) + (size_t)(par) * 256)
#define PKLP(wsp, par) ((ull*)(wsp) + 512 + (size_t)(par) * 400)
#define PKMSG(wsp)     ((ull*)(wsp) + 1312)
#define WS_SUMS 5024   // float index
#define WS_HR   5088   // float index (byte 20352, 16B aligned)
#define WS_ZERO_BYTES 20752

#define AST(p, v) __hip_atomic_store((p), (v), __ATOMIC_RELAXED, __HIP_MEMORY_SCOPE_AGENT)
#define ALD(p)    __hip_atomic_load((p), __ATOMIC_RELAXED, __HIP_MEMORY_SCOPE_AGENT)

__device__ __forceinline__ float sigf(float x) { return 1.f / (1.f + expf(-x)); }
__device__ __forceinline__ float lanebc(float v, int l) {
  return __int_as_float(__builtin_amdgcn_readlane(__float_as_int(v), l));
}
__device__ __forceinline__ ull packtv(unsigned tag, float v) {
  return ((ull)tag << 32) | (ull)__float_as_uint(v);
}
__device__ __forceinline__ float lowf(ull w) { return __uint_as_float((unsigned)w); }

#define SENDER_GATES(P, HV)                                   \
  {                                                           \
    _Pragma("unroll")                                         \
    for (int i = 0; i < 64; i += 4) {                         \
      a0 += whh[i    ] * lanebc(HV, i    );                   \
      a1 += whh[i + 1] * lanebc(HV, i + 1);                   \
      a2 += whh[i + 2] * lanebc(HV, i + 2);                   \
      a3 += whh[i + 3] * lanebc(HV, i + 3);                   \
    }                                                         \
    _Pragma("unroll")                                         \
    for (int i = 0; i < 10; i += 2) {                         \
      a0 += wih[i    ] * lanebc(sv, (P) * 10 + i    );        \
      a1 += wih[i + 1] * lanebc(sv, (P) * 10 + i + 1);        \
    }                                                         \
  }

#define RED(x) ((part[(x)] + part[100 + (x)]) + (part[200 + (x)] + part[300 + (x)]))

// ---------------- kernel 1: h0 + sender (blocks 0..9) + receiver (10) ------
// EXACT round-1 structure (proven ~122 us, VGPR=128, no spill).
__global__ __launch_bounds__(512, 2) void k_sender(
    const float* __restrict__ x,
    const float* __restrict__ W_s1,  const float* __restrict__ b_s1,
    const float* __restrict__ gum,
    const float* __restrict__ W_ih1, const float* __restrict__ W_hh1,
    const float* __restrict__ b_ih1, const float* __restrict__ b_hh1,
    const float* __restrict__ W_p,   const float* __restrict__ b_p,
    const float* __restrict__ W_ih2, const float* __restrict__ W_hh2,
    const float* __restrict__ b_ih2, const float* __restrict__ b_hh2,
    float* __restrict__ ws) {
  __shared__ float part[400];
  __shared__ float h0L[32];
  __shared__ float hx[256];     // wave-0 broadcast of exchanged h
  __shared__ float lpx[400];    // wave-0 broadcast of exchanged lp
  __shared__ float symx[VOC];   // receiver
  __shared__ int   doneL;       // receiver
  __shared__ float gL[400];     // receiver
  __shared__ float hL[HRr];     // receiver

  const int b    = blockIdx.x;
  const int t0   = threadIdx.x;
  const int lane = t0 & 63;
  const int w    = t0 >> 6;

  if (b < KS) {
    // ================= SENDER =================
    const int p    = w & 3;
    const int lr   = ((w >> 2) << 6) + lane;   // 0..127
    const bool gact = (lr < 100);
    const int gi   = lr / 25, rr = lr % 25;
    const int grow = gi * 250 + b * RPB + rr;  // global gate row

    float whh[64], wih[10], bsum = 0.f;
    if (gact) {
      #pragma unroll
      for (int i = 0; i < 64; i++) {
        int k = p * 64 + i;
        whh[i] = (k < HS) ? W_hh1[(size_t)grow * HS + k] : 0.f;
      }
      #pragma unroll
      for (int i = 0; i < 10; i++) wih[i] = W_ih1[grow * VOC + p * 10 + i];
      bsum = b_ih1[grow] + b_hh1[grow];
    }
    // wave 0: W_p slice (lane j holds W_p[j, b*25 .. +25))
    float wps[RPB];
    if (w == 0) {
      #pragma unroll
      for (int r = 0; r < RPB; r++)
        wps[r] = (lane < VOC) ? W_p[lane * HS + b * RPB + r] : 0.f;
    }
    const float bpv = (lane < VOC) ? b_p[lane] : 0.f;   // all waves (softmax)

    // ---- pre-step: h0 = relu(W_s1 @ x + b_s1), this block's 25 rows ----
    {
      const int nr = (w == 7) ? 4 : 3;
      for (int j = 0; j < nr; ++j) {
        const int r = 3 * w + j;
        const float4* wr = (const float4*)(W_s1 + (size_t)(b * RPB + r) * 4096);
        const float4* xr = (const float4*)x;
        float a0 = 0.f, a1 = 0.f, a2 = 0.f, a3 = 0.f;
        #pragma unroll
        for (int q = 0; q < 16; ++q) {
          float4 w4 = wr[lane + (q << 6)], x4 = xr[lane + (q << 6)];
          a0 += w4.x * x4.x; a1 += w4.y * x4.y; a2 += w4.z * x4.z; a3 += w4.w * x4.w;
        }
        float acc = (a0 + a1) + (a2 + a3);
        #pragma unroll
        for (int o = 32; o; o >>= 1) acc += __shfl_down(acc, o);
        if (lane == 0) h0L[r] = acc + b_s1[b * RPB + r];
      }
    }
    __syncthreads();
    if (w == 0 && lane < RPB) {    // publish h(0), tag 1 (parity 1)
      float hn0 = fmaxf(h0L[lane], 0.f);
      AST(&PKNH(ws, 1)[b * RPB + lane], packtv(1u, hn0));
    }

    float c  = 0.f;   // cell state, wave0 lanes<25
    float sv = 0.f;   // current symbol, lane-distributed
    const bool h3v = (192 + lane) < HS;   // lane < 58
    const bool l6v = lane < (400 - 384);  // lane < 16

    for (int s = 0; s <= TMAX; ++s) {
      float gv = 0.f;
      if (s > 0 && lane < VOC) gv = gum[(s - 1) * VOC + lane];

      // ---- wave-0-only merged self-tag spin: h(s) + lp(s-1..), tag s+1 ----
      if (w == 0) {
        const unsigned need = (unsigned)(s + 1);
        const int par = (s + 1) & 1;
        const ull* nhp = PKNH(ws, par);
        const ull* lpp = PKLP(ws, par);
        const bool lpact = (s > 0);
        const ull dummy = (ull)need << 32;
        ull hw0, hw1, hw2, hw3;
        ull lw0 = 0, lw1 = 0, lw2 = 0, lw3 = 0, lw4 = 0, lw5 = 0, lw6 = 0;
        for (;;) {
          hw0 = ALD(&nhp[lane]);
          hw1 = ALD(&nhp[64 + lane]);
          hw2 = ALD(&nhp[128 + lane]);
          hw3 = h3v ? ALD(&nhp[192 + lane]) : dummy;
          bool ok = (unsigned)(hw0 >> 32) == need && (unsigned)(hw1 >> 32) == need &&
                    (unsigned)(hw2 >> 32) == need && (unsigned)(hw3 >> 32) == need;
          if (lpact) {
            lw0 = ALD(&lpp[lane]);        lw1 = ALD(&lpp[64 + lane]);
            lw2 = ALD(&lpp[128 + lane]);  lw3 = ALD(&lpp[192 + lane]);
            lw4 = ALD(&lpp[256 + lane]);  lw5 = ALD(&lpp[320 + lane]);
            lw6 = l6v ? ALD(&lpp[384 + lane]) : dummy;
            ok = ok && (unsigned)(lw0 >> 32) == need && (unsigned)(lw1 >> 32) == need &&
                       (unsigned)(lw2 >> 32) == need && (unsigned)(lw3 >> 32) == need &&
                       (unsigned)(lw4 >> 32) == need && (unsigned)(lw5 >> 32) == need &&
                       (unsigned)(lw6 >> 32) == need;
          }
          if (__all(ok)) break;
        }
        hx[lane] = lowf(hw0); hx[64 + lane] = lowf(hw1); hx[128 + lane] = lowf(hw2);
        if (h3v) hx[192 + lane] = lowf(hw3);
        if (lpact) {
          lpx[lane] = lowf(lw0);        lpx[64 + lane] = lowf(lw1);
          lpx[128 + lane] = lowf(lw2);  lpx[192 + lane] = lowf(lw3);
          lpx[256 + lane] = lowf(lw4);  lpx[320 + lane] = lowf(lw5);
          if (l6v) lpx[384 + lane] = lowf(lw6);
        }
      }
      __syncthreads();   // #2: broadcast hx/lpx

      float hv0 = hx[lane], hv1 = hx[64 + lane], hv2 = hx[128 + lane];
      float hv3 = h3v ? hx[192 + lane] : 0.f;

      // ---- per-wave softmax of step s-1 (redundant across waves) ----
      if (s > 0) {
        float lg = -INFINITY;
        if (lane < VOC) {
          float acc = bpv + gv;
          #pragma unroll
          for (int m = 0; m < KS; ++m) acc += lpx[m * VOC + lane];
          lg = acc;
        }
        float v = lg; int bi = lane;
        #pragma unroll
        for (int o = 32; o; o >>= 1) {      // first-max argmax (ties -> lower lane)
          float ov = __shfl_down(v, o);
          int   oi = __shfl_down(bi, o);
          if (ov > v) { v = ov; bi = oi; }
        }
        float m  = __shfl(v, 0);
        int  idx = __shfl(bi, 0);
        float e = (lane < VOC) ? expf(lg - m) : 0.f;
        float ssum = e;
        #pragma unroll
        for (int o = 32; o; o >>= 1) ssum += __shfl_down(ssum, o);
        ssum = __shfl(ssum, 0);
        float soft = e / ssum;
        float hard = (lane == idx) ? 1.f : 0.f;
        float st   = (hard + soft) - soft;           // exact ST forward ordering
        const bool last = (s - 1 == TMAX - 1);
        float emit = last ? ((lane == VOC - 1) ? 1.f : 0.f) : st;
        const bool done = (idx == VOC - 1) || last;
        if (b == 0 && w == 0 && lane < VOC)
          AST(&PKMSG(ws)[(s - 1) * VOC + lane],
              packtv((unsigned)s | (done ? 0x10000u : 0u), emit));
        sv = (lane < VOC) ? emit : 0.f;
        if (done) break;                             // uniform across waves/blocks
      }

      // ---- gate partials: 100 rows x k-slice, all 8 waves ----
      if (gact) {
        float a0 = bsum, a1 = 0.f, a2 = 0.f, a3 = 0.f;
        if      (p == 0) SENDER_GATES(0, hv0)
        else if (p == 1) SENDER_GATES(1, hv1)
        else if (p == 2) SENDER_GATES(2, hv2)
        else             SENDER_GATES(3, hv3)
        part[p * 100 + lr] = (a0 + a1) + (a2 + a3);
      }
      __syncthreads();   // #1

      // ---- wave-0: reduce, h/c update, logit partial, publish tag s+2 ----
      if (w == 0) {
        float gi_ = RED(lane < RPB ? lane : 0);
        float gf_ = RED(25 + (lane < RPB ? lane : 0));
        float gg_ = RED(50 + (lane < RPB ? lane : 0));
        float go_ = RED(75 + (lane < RPB ? lane : 0));
        float ig = sigf(gi_), fg = sigf(gf_), gg = tanhf(gg_), og = sigf(go_);
        float cn = fg * c + ig * gg; c = cn;
        float hn = og * tanhf(cn);
        float lpsum = 0.f;
        #pragma unroll
        for (int r = 0; r < RPB; ++r) lpsum += wps[r] * lanebc(hn, r);
        const unsigned nt = (unsigned)(s + 2);
        const int np = (s + 2) & 1;
        if (lane < RPB) AST(&PKNH(ws, np)[b * RPB + lane], packtv(nt, hn));
        if (lane < VOC) AST(&PKLP(ws, np)[b * VOC + lane], packtv(nt, lpsum));
      }
    }
  } else {
    // ================= RECEIVER (concurrent consumer) =================
    const bool act = (t0 < 400);
    float wih2[VOC], whh2[HRr], bsum2 = 0.f;
    if (act) {
      #pragma unroll
      for (int i = 0; i < VOC; i++) wih2[i] = W_ih2[t0 * VOC + i];
      #pragma unroll
      for (int i = 0; i < HRr; i++) whh2[i] = W_hh2[t0 * HRr + i];
      bsum2 = b_ih2[t0] + b_hh2[t0];
    }
    float c2 = 0.f, rv0 = 0.f, rv1 = 0.f;

    for (int t = 0; t < TMAX; ++t) {
      // ---- wave-0-only spin on tagged message words ----
      if (w == 0) {
        const bool mv = (lane < VOC);
        ull mw = 0;
        for (;;) {
          if (mv) mw = ALD(&PKMSG(ws)[t * VOC + lane]);
          bool ok = !mv || ((unsigned)(mw >> 32) & 0xFFFFu) == (unsigned)(t + 1);
          if (__all(ok)) break;
        }
        if (mv) symx[lane] = lowf(mw);
        if (lane == 0) doneL = (int)(((unsigned)(mw >> 32)) >> 16);
      }
      __syncthreads();
      const bool done = (doneL != 0);
      float sv2 = (lane < VOC) ? symx[lane] : 0.f;
      if (act) {
        float a0 = bsum2, a1 = 0.f, a2 = 0.f, a3 = 0.f;
        #pragma unroll
        for (int i = 0; i < VOC; i += 4) {
          a0 += wih2[i    ] * lanebc(sv2, i    );
          a1 += wih2[i + 1] * lanebc(sv2, i + 1);
          a2 += wih2[i + 2] * lanebc(sv2, i + 2);
          a3 += wih2[i + 3] * lanebc(sv2, i + 3);
        }
        #pragma unroll
        for (int i = 0; i < 64; i += 4) {
          a0 += whh2[i    ] * lanebc(rv0, i    );
          a1 += whh2[i + 1] * lanebc(rv0, i + 1);
          a2 += whh2[i + 2] * lanebc(rv0, i + 2);
          a3 += whh2[i + 3] * lanebc(rv0, i + 3);
        }
        #pragma unroll
        for (int i = 0; i < 36; i += 4) {
          a0 += whh2[64 + i    ] * lanebc(rv1, i    );
          a1 += whh2[64 + i + 1] * lanebc(rv1, i + 1);
          a2 += whh2[64 + i + 2] * lanebc(rv1, i + 2);
          a3 += whh2[64 + i + 3] * lanebc(rv1, i + 3);
        }
        gL[t0] = (a0 + a1) + (a2 + a3);
      }
      __syncthreads();
      if (t0 < HRr) {
        float ig = sigf(gL[t0]);
        float fg = sigf(gL[100 + t0]);
        float gg = tanhf(gL[200 + t0]);
        float og = sigf(gL[300 + t0]);
        float cn = fg * c2 + ig * gg; c2 = cn;
        hL[t0] = og * tanhf(cn);
      }
      __syncthreads();
      rv0 = hL[lane];
      rv1 = (lane < 36) ? hL[64 + lane] : 0.f;
      if (done) break;
    }
    if (t0 < HRr) ws[WS_HR + t0] = hL[t0];
  }
}

// ---------------- kernel 2: logits + exp + partial sums --------------------
// One THREAD per output row: 25 independent float4 loads (no cross-lane
// reduction, no LDS tile, no transpose). Column-lockstep within a wave
// means each 128B line is consumed within 8 consecutive iterations -> L1/L2
// absorb the short-distance reuse; HBM sees one clean 105 MB stream.
__global__ __launch_bounds__(256) void k_out3(
    const float* __restrict__ W_r, const float* __restrict__ b_r,
    float* __restrict__ ws, float* __restrict__ out) {
  __shared__ float hsh[HRr];
  __shared__ float redw[4];
  const int t0 = threadIdx.x;
  if (t0 < HRr) hsh[t0] = ws[WS_HR + t0];   // kernel boundary = synced
  __syncthreads();

  const int row = blockIdx.x * 256 + t0;
  const float4* wr = (const float4*)W_r + (size_t)row * 25;
  float a0 = 0.f, a1 = 0.f, a2 = 0.f, a3 = 0.f;
  #pragma unroll
  for (int c = 0; c < 25; ++c) {
    float4 w4 = wr[c];                       // per-thread row stream
    a0 += w4.x * hsh[4 * c];                 // hsh: uniform addr = broadcast
    a1 += w4.y * hsh[4 * c + 1];
    a2 += w4.z * hsh[4 * c + 2];
    a3 += w4.w * hsh[4 * c + 3];
  }
  float e = expf((a0 + a1) + (a2 + a3) + b_r[row]);
  out[row] = e;                              // fully coalesced store

  // block partial sum -> one atomic per block
  float s = e;
  #pragma unroll
  for (int o = 32; o; o >>= 1) s += __shfl_down(s, o);
  if ((t0 & 63) == 0) redw[t0 >> 6] = s;
  __syncthreads();
  if (t0 == 0)
    atomicAdd(&ws[WS_SUMS + (blockIdx.x & 63)],
              (redw[0] + redw[1]) + (redw[2] + redw[3]));
}

// ---------------- kernel 3: out *= 1/sum -----------------------------------
__global__ __launch_bounds__(256) void k_scale(const float* __restrict__ ws,
                                               float* __restrict__ out) {
  float s = ws[WS_SUMS + (threadIdx.x & 63)];
  #pragma unroll
  for (int o = 1; o < 64; o <<= 1) s += __shfl_xor(s, o);   // identical all lanes
  const float rinv = 1.f / s;
  const int i = blockIdx.x * 256 + threadIdx.x;   // float4 index
  float4 e = ((const float4*)out)[i];
  e.x *= rinv; e.y *= rinv; e.z *= rinv; e.w *= rinv;
  ((float4*)out)[i] = e;
}

extern "C" void kernel_launch(void* const* d_in, const int* in_sizes, int n_in,
                              void* d_out, int out_size, void* d_ws, size_t ws_size,
                              hipStream_t stream) {
  const float* x     = (const float*)d_in[0];
  const float* gum   = (const float*)d_in[1];
  const float* W_s1  = (const float*)d_in[2];
  const float* b_s1  = (const float*)d_in[3];
  const float* W_ih1 = (const float*)d_in[4];
  const float* W_hh1 = (const float*)d_in[5];
  const float* b_ih1 = (const float*)d_in[6];
  const float* b_hh1 = (const float*)d_in[7];
  const float* W_p   = (const float*)d_in[8];
  const float* b_p   = (const float*)d_in[9];
  const float* W_ih2 = (const float*)d_in[10];
  const float* W_hh2 = (const float*)d_in[11];
  const float* b_ih2 = (const float*)d_in[12];
  const float* b_hh2 = (const float*)d_in[13];
  const float* W_r   = (const float*)d_in[14];
  const float* b_r   = (const float*)d_in[15];
  float* ws  = (float*)d_ws;
  float* out = (float*)d_out;

  // zero packed tag regions + sum slots (ws re-poisoned 0xAA every launch)
  (void)hipMemsetAsync(d_ws, 0, WS_ZERO_BYTES, stream);
  k_sender<<<KS + 1,    512, 0, stream>>>(x, W_s1, b_s1, gum, W_ih1, W_hh1,
                                          b_ih1, b_hh1, W_p, b_p,
                                          W_ih2, W_hh2, b_ih2, b_hh2, ws);
  k_out3  <<<NCLS/256,  256, 0, stream>>>(W_r, b_r, ws, out);
  k_scale <<<NCLS/1024, 256, 0, stream>>>(ws, out);
}

// Round 9
// 304.338 us; speedup vs baseline: 1.5412x; 1.0531x over previous
//
#include <hip/hip_runtime.h>
#include <math.h>

// Problem constants (from reference)
#define HS    250      // sender hidden
#define HRr   100      // receiver hidden
#define VOC   40       // vocab, EOS = 39
#define TMAX  30       // max message length
#define NCLS  262144   // output classes
#define KS    10       // sender blocks (each owns 25 h-rows = 100 gate rows)
#define RPB   25       // h-rows per sender block

typedef unsigned long long ull;

// ws layout. Packed (tag<<32 | float) regions first, 8B-aligned:
//   PK_NH : ull[2][256]  h exchange, double-buffered by tag parity
//   PK_LP : ull[2][400]  logit partials, double-buffered
//   PK_MSG: ull[30*40]   message symbols (tag carries done bit)
// Floats after: WS_SUMS float[64] @byte 20096; WS_HR float[100] @byte 20352.
#define PKNH(wsp, par) ((ull*)(wsp) + (size_t)(par) * 256)
#define PKLP(wsp, par) ((ull*)(wsp) + 512 + (size_t)(par) * 400)
#define PKMSG(wsp)     ((ull*)(wsp) + 1312)
#define WS_SUMS 5024   // float index
#define WS_HR   5088   // float index (byte 20352, 16B aligned)
#define WS_ZERO_BYTES 20352

#define TG(wv) ((unsigned)((wv) >> 32))

__device__ __forceinline__ float sigf(float x) { return 1.f / (1.f + expf(-x)); }
__device__ __forceinline__ float lanebc(float v, int l) {
  return __int_as_float(__builtin_amdgcn_readlane(__float_as_int(v), l));
}
__device__ __forceinline__ ull packtv(unsigned tag, float v) {
  return ((ull)tag << 32) | (ull)__float_as_uint(v);
}
__device__ __forceinline__ float lowf(ull w) { return __uint_as_float((unsigned)w); }

// Exchange ops: explicit sc0 sc1 (bypass L1 AND L2 -> served at LLC).
// The tagged-word protocol needs no inter-word ordering; these are the
// weakest-ordering / strongest-visibility ops that are correct.
__device__ __forceinline__ void st_llc(ull* p, ull v) {
  asm volatile("global_store_dwordx2 %0, %1, off sc0 sc1"
               :: "v"(p), "v"(v) : "memory");
}
__device__ __forceinline__ ull ld_llc(const ull* p) {
  ull r;
  asm volatile("global_load_dwordx2 %0, %1, off sc0 sc1\n\t"
               "s_waitcnt vmcnt(0)"
               : "=v"(r) : "v"(p) : "memory");
  return r;
}

#define SENDER_GATES(P, HV)                                   \
  {                                                           \
    _Pragma("unroll")                                         \
    for (int i = 0; i < 64; i += 4) {                         \
      a0 += whh[i    ] * lanebc(HV, i    );                   \
      a1 += whh[i + 1] * lanebc(HV, i + 1);                   \
      a2 += whh[i + 2] * lanebc(HV, i + 2);                   \
      a3 += whh[i + 3] * lanebc(HV, i + 3);                   \
    }                                                         \
    _Pragma("unroll")                                         \
    for (int i = 0; i < 10; i += 2) {                         \
      a0 += wih[i    ] * lanebc(sv, (P) * 10 + i    );        \
      a1 += wih[i + 1] * lanebc(sv, (P) * 10 + i + 1);        \
    }                                                         \
  }

#define RED(x) ((part[(x)] + part[100 + (x)]) + (part[200 + (x)] + part[300 + (x)]))

// ---------------- kernel 1: h0 + sender (blocks 0..9) + receiver (10) ------
// Round-1 structure; ONLY the exchange memory ops changed to sc0 sc1 asm.
__global__ __launch_bounds__(512, 2) void k_sender(
    const float* __restrict__ x,
    const float* __restrict__ W_s1,  const float* __restrict__ b_s1,
    const float* __restrict__ gum,
    const float* __restrict__ W_ih1, const float* __restrict__ W_hh1,
    const float* __restrict__ b_ih1, const float* __restrict__ b_hh1,
    const float* __restrict__ W_p,   const float* __restrict__ b_p,
    const float* __restrict__ W_ih2, const float* __restrict__ W_hh2,
    const float* __restrict__ b_ih2, const float* __restrict__ b_hh2,
    float* __restrict__ ws) {
  __shared__ float part[400];
  __shared__ float h0L[32];
  __shared__ float hx[256];     // wave-0 broadcast of exchanged h
  __shared__ float lpx[400];    // wave-0 broadcast of exchanged lp
  __shared__ float symx[VOC];   // receiver
  __shared__ int   doneL;       // receiver
  __shared__ float gL[400];     // receiver
  __shared__ float hL[HRr];     // receiver

  const int b    = blockIdx.x;
  const int t0   = threadIdx.x;
  const int lane = t0 & 63;
  const int w    = t0 >> 6;

  if (b < KS) {
    // ================= SENDER =================
    const int p    = w & 3;
    const int lr   = ((w >> 2) << 6) + lane;   // 0..127
    const bool gact = (lr < 100);
    const int gi   = lr / 25, rr = lr % 25;
    const int grow = gi * 250 + b * RPB + rr;  // global gate row

    float whh[64], wih[10], bsum = 0.f;
    if (gact) {
      #pragma unroll
      for (int i = 0; i < 64; i++) {
        int k = p * 64 + i;
        whh[i] = (k < HS) ? W_hh1[(size_t)grow * HS + k] : 0.f;
      }
      #pragma unroll
      for (int i = 0; i < 10; i++) wih[i] = W_ih1[grow * VOC + p * 10 + i];
      bsum = b_ih1[grow] + b_hh1[grow];
    }
    // wave 0: W_p slice (lane j holds W_p[j, b*25 .. +25))
    float wps[RPB];
    if (w == 0) {
      #pragma unroll
      for (int r = 0; r < RPB; r++)
        wps[r] = (lane < VOC) ? W_p[lane * HS + b * RPB + r] : 0.f;
    }
    const float bpv = (lane < VOC) ? b_p[lane] : 0.f;   // all waves (softmax)

    // ---- pre-step: h0 = relu(W_s1 @ x + b_s1), this block's 25 rows ----
    {
      const int nr = (w == 7) ? 4 : 3;
      for (int j = 0; j < nr; ++j) {
        const int r = 3 * w + j;
        const float4* wr = (const float4*)(W_s1 + (size_t)(b * RPB + r) * 4096);
        const float4* xr = (const float4*)x;
        float a0 = 0.f, a1 = 0.f, a2 = 0.f, a3 = 0.f;
        #pragma unroll
        for (int q = 0; q < 16; ++q) {
          float4 w4 = wr[lane + (q << 6)], x4 = xr[lane + (q << 6)];
          a0 += w4.x * x4.x; a1 += w4.y * x4.y; a2 += w4.z * x4.z; a3 += w4.w * x4.w;
        }
        float acc = (a0 + a1) + (a2 + a3);
        #pragma unroll
        for (int o = 32; o; o >>= 1) acc += __shfl_down(acc, o);
        if (lane == 0) h0L[r] = acc + b_s1[b * RPB + r];
      }
    }
    __syncthreads();
    if (w == 0 && lane < RPB) {    // publish h(0), tag 1 (parity 1)
      float hn0 = fmaxf(h0L[lane], 0.f);
      st_llc(&PKNH(ws, 1)[b * RPB + lane], packtv(1u, hn0));
    }

    float c  = 0.f;   // cell state, wave0 lanes<25
    float sv = 0.f;   // current symbol, lane-distributed
    const bool h3v = (192 + lane) < HS;   // lane < 58
    const bool l6v = lane < (400 - 384);  // lane < 16

    for (int s = 0; s <= TMAX; ++s) {
      float gv = 0.f;
      if (s > 0 && lane < VOC) gv = gum[(s - 1) * VOC + lane];

      // ---- wave-0-only merged self-tag spin: h(s) + lp(s-1..), tag s+1 ----
      if (w == 0) {
        const unsigned need = (unsigned)(s + 1);
        const int par = (s + 1) & 1;
        const ull* nhp = PKNH(ws, par);
        const ull* lpp = PKLP(ws, par);
        const bool lpact = (s > 0);
        // Unconditional addresses; out-of-range lanes read neighboring ws
        // regions (harmless), tag checks below are guarded by h3v/l6v.
        const ull* pn0 = nhp + lane;        const ull* pn1 = nhp + 64 + lane;
        const ull* pn2 = nhp + 128 + lane;  const ull* pn3 = nhp + 192 + lane;
        const ull* pl0 = lpp + lane;        const ull* pl1 = lpp + 64 + lane;
        const ull* pl2 = lpp + 128 + lane;  const ull* pl3 = lpp + 192 + lane;
        const ull* pl4 = lpp + 256 + lane;  const ull* pl5 = lpp + 320 + lane;
        const ull* pl6 = lpp + 384 + lane;
        ull hw0, hw1, hw2, hw3, lw0, lw1, lw2, lw3, lw4, lw5, lw6;
        for (;;) {
          // batched LLC poll: 11 sc0 sc1 loads, ONE waitcnt
          asm volatile(
            "global_load_dwordx2 %0, %11, off sc0 sc1\n\t"
            "global_load_dwordx2 %1, %12, off sc0 sc1\n\t"
            "global_load_dwordx2 %2, %13, off sc0 sc1\n\t"
            "global_load_dwordx2 %3, %14, off sc0 sc1\n\t"
            "global_load_dwordx2 %4, %15, off sc0 sc1\n\t"
            "global_load_dwordx2 %5, %16, off sc0 sc1\n\t"
            "global_load_dwordx2 %6, %17, off sc0 sc1\n\t"
            "global_load_dwordx2 %7, %18, off sc0 sc1\n\t"
            "global_load_dwordx2 %8, %19, off sc0 sc1\n\t"
            "global_load_dwordx2 %9, %20, off sc0 sc1\n\t"
            "global_load_dwordx2 %10, %21, off sc0 sc1\n\t"
            "s_waitcnt vmcnt(0)"
            : "=&v"(hw0), "=&v"(hw1), "=&v"(hw2), "=&v"(hw3),
              "=&v"(lw0), "=&v"(lw1), "=&v"(lw2), "=&v"(lw3),
              "=&v"(lw4), "=&v"(lw5), "=&v"(lw6)
            : "v"(pn0), "v"(pn1), "v"(pn2), "v"(pn3),
              "v"(pl0), "v"(pl1), "v"(pl2), "v"(pl3),
              "v"(pl4), "v"(pl5), "v"(pl6)
            : "memory");
          bool ok = TG(hw0) == need && TG(hw1) == need && TG(hw2) == need &&
                    (!h3v || TG(hw3) == need);
          if (lpact) {
            ok = ok && TG(lw0) == need && TG(lw1) == need && TG(lw2) == need &&
                       TG(lw3) == need && TG(lw4) == need && TG(lw5) == need &&
                       (!l6v || TG(lw6) == need);
          }
          if (__all(ok)) break;
        }
        hx[lane] = lowf(hw0); hx[64 + lane] = lowf(hw1); hx[128 + lane] = lowf(hw2);
        if (h3v) hx[192 + lane] = lowf(hw3);
        if (lpact) {
          lpx[lane] = lowf(lw0);        lpx[64 + lane] = lowf(lw1);
          lpx[128 + lane] = lowf(lw2);  lpx[192 + lane] = lowf(lw3);
          lpx[256 + lane] = lowf(lw4);  lpx[320 + lane] = lowf(lw5);
          if (l6v) lpx[384 + lane] = lowf(lw6);
        }
      }
      __syncthreads();   // #2: broadcast hx/lpx

      float hv0 = hx[lane], hv1 = hx[64 + lane], hv2 = hx[128 + lane];
      float hv3 = h3v ? hx[192 + lane] : 0.f;

      // ---- per-wave softmax of step s-1 (redundant across waves) ----
      if (s > 0) {
        float lg = -INFINITY;
        if (lane < VOC) {
          float acc = bpv + gv;
          #pragma unroll
          for (int m = 0; m < KS; ++m) acc += lpx[m * VOC + lane];
          lg = acc;
        }
        float v = lg; int bi = lane;
        #pragma unroll
        for (int o = 32; o; o >>= 1) {      // first-max argmax (ties -> lower lane)
          float ov = __shfl_down(v, o);
          int   oi = __shfl_down(bi, o);
          if (ov > v) { v = ov; bi = oi; }
        }
        float m  = __shfl(v, 0);
        int  idx = __shfl(bi, 0);
        float e = (lane < VOC) ? expf(lg - m) : 0.f;
        float ssum = e;
        #pragma unroll
        for (int o = 32; o; o >>= 1) ssum += __shfl_down(ssum, o);
        ssum = __shfl(ssum, 0);
        float soft = e / ssum;
        float hard = (lane == idx) ? 1.f : 0.f;
        float st   = (hard + soft) - soft;           // exact ST forward ordering
        const bool last = (s - 1 == TMAX - 1);
        float emit = last ? ((lane == VOC - 1) ? 1.f : 0.f) : st;
        const bool done = (idx == VOC - 1) || last;
        if (b == 0 && w == 0 && lane < VOC)
          st_llc(&PKMSG(ws)[(s - 1) * VOC + lane],
                 packtv((unsigned)s | (done ? 0x10000u : 0u), emit));
        sv = (lane < VOC) ? emit : 0.f;
        if (done) break;                             // uniform across waves/blocks
      }

      // ---- gate partials: 100 rows x k-slice, all 8 waves ----
      if (gact) {
        float a0 = bsum, a1 = 0.f, a2 = 0.f, a3 = 0.f;
        if      (p == 0) SENDER_GATES(0, hv0)
        else if (p == 1) SENDER_GATES(1, hv1)
        else if (p == 2) SENDER_GATES(2, hv2)
        else             SENDER_GATES(3, hv3)
        part[p * 100 + lr] = (a0 + a1) + (a2 + a3);
      }
      __syncthreads();   // #1

      // ---- wave-0: reduce, h/c update, logit partial, publish tag s+2 ----
      if (w == 0) {
        float gi_ = RED(lane < RPB ? lane : 0);
        float gf_ = RED(25 + (lane < RPB ? lane : 0));
        float gg_ = RED(50 + (lane < RPB ? lane : 0));
        float go_ = RED(75 + (lane < RPB ? lane : 0));
        float ig = sigf(gi_), fg = sigf(gf_), gg = tanhf(gg_), og = sigf(go_);
        float cn = fg * c + ig * gg; c = cn;
        float hn = og * tanhf(cn);
        float lpsum = 0.f;
        #pragma unroll
        for (int r = 0; r < RPB; ++r) lpsum += wps[r] * lanebc(hn, r);
        const unsigned nt = (unsigned)(s + 2);
        const int np = (s + 2) & 1;
        if (lane < RPB) st_llc(&PKNH(ws, np)[b * RPB + lane], packtv(nt, hn));
        if (lane < VOC) st_llc(&PKLP(ws, np)[b * VOC + lane], packtv(nt, lpsum));
      }
    }
  } else {
    // ================= RECEIVER (concurrent consumer) =================
    const bool act = (t0 < 400);
    float wih2[VOC], whh2[HRr], bsum2 = 0.f;
    if (act) {
      #pragma unroll
      for (int i = 0; i < VOC; i++) wih2[i] = W_ih2[t0 * VOC + i];
      #pragma unroll
      for (int i = 0; i < HRr; i++) whh2[i] = W_hh2[t0 * HRr + i];
      bsum2 = b_ih2[t0] + b_hh2[t0];
    }
    float c2 = 0.f, rv0 = 0.f, rv1 = 0.f;

    for (int t = 0; t < TMAX; ++t) {
      // ---- wave-0-only spin on tagged message words ----
      if (w == 0) {
        const bool mv = (lane < VOC);
        ull mw = 0;
        for (;;) {
          if (mv) mw = ld_llc(&PKMSG(ws)[t * VOC + lane]);
          bool ok = !mv || ((unsigned)(mw >> 32) & 0xFFFFu) == (unsigned)(t + 1);
          if (__all(ok)) break;
        }
        if (mv) symx[lane] = lowf(mw);
        if (lane == 0) doneL = (int)(((unsigned)(mw >> 32)) >> 16);
      }
      __syncthreads();
      const bool done = (doneL != 0);
      float sv2 = (lane < VOC) ? symx[lane] : 0.f;
      if (act) {
        float a0 = bsum2, a1 = 0.f, a2 = 0.f, a3 = 0.f;
        #pragma unroll
        for (int i = 0; i < VOC; i += 4) {
          a0 += wih2[i    ] * lanebc(sv2, i    );
          a1 += wih2[i + 1] * lanebc(sv2, i + 1);
          a2 += wih2[i + 2] * lanebc(sv2, i + 2);
          a3 += wih2[i + 3] * lanebc(sv2, i + 3);
        }
        #pragma unroll
        for (int i = 0; i < 64; i += 4) {
          a0 += whh2[i    ] * lanebc(rv0, i    );
          a1 += whh2[i + 1] * lanebc(rv0, i + 1);
          a2 += whh2[i + 2] * lanebc(rv0, i + 2);
          a3 += whh2[i + 3] * lanebc(rv0, i + 3);
        }
        #pragma unroll
        for (int i = 0; i < 36; i += 4) {
          a0 += whh2[64 + i    ] * lanebc(rv1, i    );
          a1 += whh2[64 + i + 1] * lanebc(rv1, i + 1);
          a2 += whh2[64 + i + 2] * lanebc(rv1, i + 2);
          a3 += whh2[64 + i + 3] * lanebc(rv1, i + 3);
        }
        gL[t0] = (a0 + a1) + (a2 + a3);
      }
      __syncthreads();
      if (t0 < HRr) {
        float ig = sigf(gL[t0]);
        float fg = sigf(gL[100 + t0]);
        float gg = tanhf(gL[200 + t0]);
        float og = sigf(gL[300 + t0]);
        float cn = fg * c2 + ig * gg; c2 = cn;
        hL[t0] = og * tanhf(cn);
      }
      __syncthreads();
      rv0 = hL[lane];
      rv1 = (lane < 36) ? hL[64 + lane] : 0.f;
      if (done) break;
    }
    if (t0 < HRr) ws[WS_HR + t0] = hL[t0];
  }
}

// ---------------- kernel 2: logits + exp + partial sums (105 MB HBM) -------
__global__ __launch_bounds__(256) void k_out(
    const float* __restrict__ W_r, const float* __restrict__ b_r,
    float* __restrict__ ws, float* __restrict__ out) {
  __shared__ float4 h4[25];
  __shared__ float  red[4];
  const int t0 = threadIdx.x;
  if (t0 < 25) h4[t0] = ((const float4*)(ws + WS_HR))[t0];
  __syncthreads();
  const int lane = t0 & 63;
  const int wv   = t0 >> 6;
  const int sl   = lane & 31;
  const int hf   = lane >> 5;
  const int base = blockIdx.x * 128 + wv * 32;
  float accs = 0.f;
  #pragma unroll 4
  for (int i = 0; i < 16; ++i) {
    const int row = base + 2 * i + hf;
    float v = 0.f;
    if (sl < 25) {
      float4 w4 = ((const float4*)W_r)[(size_t)row * 25 + sl];
      float4 hq = h4[sl];
      v = w4.x * hq.x + w4.y * hq.y + w4.z * hq.z + w4.w * hq.w;
    }
    #pragma unroll
    for (int o = 16; o; o >>= 1) v += __shfl_down(v, o, 32);
    float e = 0.f;
    if (sl == 0) { e = expf(v + b_r[row]); accs += e; }
    float eB = __shfl(e, 32);
    if (lane == 0) ((float2*)out)[(base + 2 * i) >> 1] = make_float2(e, eB);
  }
  accs += __shfl_down(accs, 32);     // lane0 += lane32
  if (lane == 0) red[wv] = accs;
  __syncthreads();
  if (t0 == 0)
    atomicAdd(&ws[WS_SUMS + (blockIdx.x & 63)], (red[0] + red[1]) + (red[2] + red[3]));
}

// ---------------- kernel 3: out *= 1/sum -----------------------------------
__global__ __launch_bounds__(256) void k_scale(const float* __restrict__ ws,
                                               float* __restrict__ out) {
  float s = ws[WS_SUMS + (threadIdx.x & 63)];
  #pragma unroll
  for (int o = 1; o < 64; o <<= 1) s += __shfl_xor(s, o);   // identical all lanes
  const float rinv = 1.f / s;
  const int i = blockIdx.x * 256 + threadIdx.x;   // float4 index
  float4 e = ((const float4*)out)[i];
  e.x *= rinv; e.y *= rinv; e.z *= rinv; e.w *= rinv;
  ((float4*)out)[i] = e;
}

extern "C" void kernel_launch(void* const* d_in, const int* in_sizes, int n_in,
                              void* d_out, int out_size, void* d_ws, size_t ws_size,
                              hipStream_t stream) {
  const float* x     = (const float*)d_in[0];
  const float* gum   = (const float*)d_in[1];
  const float* W_s1  = (const float*)d_in[2];
  const float* b_s1  = (const float*)d_in[3];
  const float* W_ih1 = (const float*)d_in[4];
  const float* W_hh1 = (const float*)d_in[5];
  const float* b_ih1 = (const float*)d_in[6];
  const float* b_hh1 = (const float*)d_in[7];
  const float* W_p   = (const float*)d_in[8];
  const float* b_p   = (const float*)d_in[9];
  const float* W_ih2 = (const float*)d_in[10];
  const float* W_hh2 = (const float*)d_in[11];
  const float* b_ih2 = (const float*)d_in[12];
  const float* b_hh2 = (const float*)d_in[13];
  const float* W_r   = (const float*)d_in[14];
  const float* b_r   = (const float*)d_in[15];
  float* ws  = (float*)d_ws;
  float* out = (float*)d_out;

  // zero packed tag regions + sum slots (ws re-poisoned 0xAA every launch)
  (void)hipMemsetAsync(d_ws, 0, WS_ZERO_BYTES, stream);
  k_sender<<<KS + 1,   512, 0, stream>>>(x, W_s1, b_s1, gum, W_ih1, W_hh1,
                                         b_ih1, b_hh1, W_p, b_p,
                                         W_ih2, W_hh2, b_ih2, b_hh2, ws);
  k_out   <<<NCLS/128, 256, 0, stream>>>(W_r, b_r, ws, out);
  k_scale <<<NCLS/1024,256, 0, stream>>>(ws, out);
}